// Round 6
// baseline (1177.621 us; speedup 1.0000x reference)
//
#include <hip/hip_runtime.h>

#define L_SEQ 512
#define B_SZ  1024
#define HD    64

// LDS strides in floats. WSTR=132: row stride 528 B (16-B aligned); word index
// of (j,k) is 132*j + k == 4*j + k (mod 32), so the 16 broadcast addresses of a
// wave's b128 weight read land 2-per-bank-quad -> 2-way conflict (free, m136).
#define WSTR 132
#define XSTR 132
#define RSTR 68

__device__ __forceinline__ float fast_sigmoid(float x) {
    return __builtin_amdgcn_rcpf(1.0f + __builtin_amdgcn_exp2f(-1.4426950408889634f * x));
}
__device__ __forceinline__ float fast_tanh(float x) {
    return 1.0f - 2.0f * __builtin_amdgcn_rcpf(1.0f + __builtin_amdgcn_exp2f(2.8853900817779268f * x));
}

// NQ float4-quads of dot product from two LDS streams; 4 rotating accumulators.
template <int NQ>
__device__ __forceinline__ float dotq(const float4* W4, const float4* X4) {
    float a0 = 0.f, a1 = 0.f, a2 = 0.f, a3 = 0.f;
#pragma unroll
    for (int q = 0; q < NQ; q += 4) {
        float4 w, x;
        w = W4[q + 0]; x = X4[q + 0];
        a0 = fmaf(w.x, x.x, a0); a0 = fmaf(w.y, x.y, a0);
        a0 = fmaf(w.z, x.z, a0); a0 = fmaf(w.w, x.w, a0);
        w = W4[q + 1]; x = X4[q + 1];
        a1 = fmaf(w.x, x.x, a1); a1 = fmaf(w.y, x.y, a1);
        a1 = fmaf(w.z, x.z, a1); a1 = fmaf(w.w, x.w, a1);
        w = W4[q + 2]; x = X4[q + 2];
        a2 = fmaf(w.x, x.x, a2); a2 = fmaf(w.y, x.y, a2);
        a2 = fmaf(w.z, x.z, a2); a2 = fmaf(w.w, x.w, a2);
        w = W4[q + 3]; x = X4[q + 3];
        a3 = fmaf(w.x, x.x, a3); a3 = fmaf(w.y, x.y, a3);
        a3 = fmaf(w.z, x.z, a3); a3 = fmaf(w.w, x.w, a3);
    }
    return (a0 + a1) + (a2 + a3);
}

// 256 blocks x 768 threads (12 waves). Block = one CU = 4 batch rows, all 512
// steps. Wave wv: gate = wv%3 (z/r/cand), jc = wv/3 (16-col chunk). Lane:
// b = lane&3 (batch row), jj = lane>>2, j = jc*16+jj. All weights live in LDS
// (transposed [gate][j][k], padded stride); weight reads are 4-way broadcast
// b128, xh reads 16-way broadcast b128. Each wave computes full 128-k dots ->
// no partial-sum reductions; 2 barriers/step.
__global__ __launch_bounds__(768, 3) void gru_fused_kernel(
    const int* __restrict__ xind, const float* __restrict__ emb,
    const float* __restrict__ Wz, const float* __restrict__ Wr,
    const float* __restrict__ Wh, float* __restrict__ out)
{
    __shared__ __align__(16) float sW[3][64 * WSTR]; // [gate][j*WSTR + k]
    __shared__ __align__(16) float sXH[4][XSTR];     // [b][k]: k<64 x, k>=64 h
    __shared__ __align__(16) float sRH[4][RSTR];     // [b][k] r*h
    __shared__ __align__(16) float sZ[4][RSTR];      // [b][j] z gate

    const int tid  = threadIdx.x;
    const int lane = tid & 63;
    const int wv   = tid >> 6;        // 0..11
    const int gate = wv % 3;          // 0=z 1=r 2=cand (balanced per SIMD)
    const int jc   = wv / 3;          // 0..3
    const int b    = lane & 3;
    const int jj   = lane >> 2;
    const int j    = jc * 16 + jj;
    const int row0 = blockIdx.x * 4;

    // ---- weights global [k][j] -> LDS transposed [g][j][k] (one-time) ----
    for (int i = tid; i < 3 * 8192; i += 768) {
        const int g = i >> 13, rem = i & 8191;
        const int k = rem >> 6, jw = rem & 63;
        const float* Wg = (g == 0) ? Wz : (g == 1) ? Wr : Wh;
        sW[g][jw * WSTR + k] = Wg[rem];
    }
    // ---- state init: x(0) rows, h = 0 ----
    if (wv < 4) {
        const int idx0 = xind[row0 + wv];
        sXH[wv][lane] = emb[(size_t)idx0 * HD + lane];
    } else if (wv < 8) {
        sXH[wv - 4][64 + lane] = 0.0f;
    }
    int idxn = 0;
    if (gate == 0) idxn = xind[B_SZ + row0 + jc];   // index for t=1
    __syncthreads();

    // Wz/Wr rows: 0..63 multiply x, 64..127 multiply h  -> full 128-k dot.
    // Wh rows:    0..63 multiply r*h, 64..127 multiply x.
    const float*  wrow = &sW[gate][j * WSTR];
    const float4* X4   = (const float4*)(&sXH[b][0]);
    const float4* R4   = (const float4*)(&sRH[b][0]);
    float* obase = out + (size_t)(row0 + b) * HD + j;

    float accC = 0.0f;
    for (int t = 0; t < L_SEQ; ++t) {
        // ---- prefetch: emb row for t+1 (z waves; load issued before dot) ----
        float ev = 0.0f;
        if (gate == 0 && t < L_SEQ - 1)
            ev = emb[(size_t)idxn * HD + lane];

        // ---- Phase A ----
        if (gate < 2) {
            const float s = dotq<32>((const float4*)wrow, X4);   // full xh dot
            const float g = fast_sigmoid(s);
            if (gate == 0) sZ[b][j] = g;
            else           sRH[b][j] = g * sXH[b][64 + j];       // r * h
        } else {
            accC = dotq<16>((const float4*)(wrow + 64), X4);     // x-part of cand
        }
        __syncthreads();

        // ---- Phase B ----
        if (gate == 2) {
            const float s  = accC + dotq<16>((const float4*)wrow, R4); // rh-part
            const float hc = fast_tanh(s);
            const float z  = sZ[b][j];
            const float ho = sXH[b][64 + j];
            const float hn = fmaf(z, hc - ho, ho);
            sXH[b][64 + j] = hn;
            obase[(size_t)t * (B_SZ * HD)] = hn;
            if (t == L_SEQ - 1)
                out[(size_t)L_SEQ * B_SZ * HD + (size_t)(row0 + b) * HD + j] = hn;
        } else if (gate == 0) {
            if (t < L_SEQ - 1) sXH[jc][lane] = ev;               // commit x(t+1)
            if (t < L_SEQ - 2) idxn = xind[(size_t)(t + 2) * B_SZ + row0 + jc];
        }
        __syncthreads();
    }
}

extern "C" void kernel_launch(void* const* d_in, const int* in_sizes, int n_in,
                              void* d_out, int out_size, void* d_ws, size_t ws_size,
                              hipStream_t stream) {
    (void)in_sizes; (void)n_in; (void)out_size; (void)d_ws; (void)ws_size;
    const int*   x   = (const int*)  d_in[0];
    const float* emb = (const float*)d_in[1];
    const float* Wz  = (const float*)d_in[2];
    const float* Wr  = (const float*)d_in[3];
    const float* Wh  = (const float*)d_in[4];
    float* out = (float*)d_out;

    gru_fused_kernel<<<dim3(B_SZ / 4), dim3(768), 0, stream>>>(x, emb, Wz, Wr, Wh, out);
}

// Round 9
// 1074.597 us; speedup vs baseline: 1.0959x; 1.0959x over previous
//
#include <hip/hip_runtime.h>

#define L_SEQ 512
#define B_SZ  1024
#define HD    64
#define WSTRF 132              // weight row stride in floats (33 quads: conflict-free unique reads)

__device__ __forceinline__ float fast_sigmoid(float x) {
    return __builtin_amdgcn_rcpf(1.0f + __builtin_amdgcn_exp2f(-1.4426950408889634f * x));
}
__device__ __forceinline__ float fast_tanh(float x) {
    return 1.0f - 2.0f * __builtin_amdgcn_rcpf(1.0f + __builtin_amdgcn_exp2f(2.8853900817779268f * x));
}
__device__ __forceinline__ float dot4(float4 a, float4 b, float acc) {
    acc = fmaf(a.x, b.x, acc); acc = fmaf(a.y, b.y, acc);
    acc = fmaf(a.z, b.z, acc); acc = fmaf(a.w, b.w, acc);
    return acc;
}

// 256 blocks x 512 threads (8 waves). Block = 1 CU = 4 batch rows, all 512 steps.
// Lane = output column j. Wave wv owns k-slice [16*wv, 16*wv+16).
//   z,r: slice indexes xh = [x|h].  cand: slice indexes [rh|x] — waves 4-7 get the
//   x-part (phase A), waves 0-3 the rh-part (phase B) -> each SIMD hosts one
//   A-heavy + one B-heavy wave (balanced).
// All LDS operand reads are per-lane-unique b128 (weights, quad-stride 33) or
// per-row quads; each weight quad is reused across 4 rows (register blocking).
// Partials: [g][b][wv][j] -> writes lane-consecutive, reduce reads 8 conflict-free b32.
__global__ __launch_bounds__(512, 2) void gru_fused_kernel(
    const int* __restrict__ xind, const float* __restrict__ emb,
    const float* __restrict__ Wz, const float* __restrict__ Wr,
    const float* __restrict__ Wh, float* __restrict__ out)
{
    __shared__ __align__(16) float sW[3 * 64 * WSTRF];   // [g][j][k] 101376 B
    __shared__ __align__(16) float sXH[4][128];          // [b][ x(0..63) | h(64..127) ]
    __shared__ __align__(16) float sRH[4][64];           // r*h
    __shared__ __align__(16) float sZ[4][64];            // z gate
    __shared__ __align__(16) float sPA[2][4][8][64];     // z/r partials [g][b][wv][j]
    __shared__ __align__(16) float sPC[4][8][64];        // cand partials [b][wv][j]

    const int tid = threadIdx.x;
    const int j   = tid & 63;
    const int wv  = tid >> 6;          // 0..7
    const int k0  = wv * 16;           // this wave's k-slice
    const bool isE = (k0 >= 64);       // waves 4..7: cand-x in phase A
    const int bE  = wv - 4;            // E-wave's prefetch row
    const int row0 = blockIdx.x * 4;

    // ---- one-time: weights global [k][j] -> LDS [g][j*WSTRF + k] ----
    for (int i = tid; i < 3 * 128 * 64; i += 512) {
        const int g = i >> 13, rem = i & 8191;
        const int k = rem >> 6, jj = rem & 63;
        const float* Wg = (g == 0) ? Wz : (g == 1) ? Wr : Wh;
        sW[g * (64 * WSTRF) + jj * WSTRF + k] = Wg[rem];
    }
    // ---- state init: x(0), h = 0 ----
    if (!isE) {
        sXH[wv][64 + j] = 0.0f;
    } else {
        sXH[bE][j] = emb[(size_t)xind[row0 + bE] * HD + j];
    }
    __syncthreads();

    const float* bz = &sW[j * WSTRF + k0];
    const float* br = bz + 64 * WSTRF;
    const float* bc = br + 64 * WSTRF;

    for (int t = 0; t < L_SEQ; ++t) {
        // ---- prefetch next-step embedding (E waves), hidden under phase A/B ----
        float ev = 0.0f;
        if (isE && t < L_SEQ - 1) {
            const int idxn = xind[(size_t)(t + 1) * B_SZ + row0 + bE];
            ev = emb[(size_t)idxn * HD + j];
        }

        // ---- Phase A: z,r slices (all waves) + cand-x (E waves) ----
        float az[4] = {0.f, 0.f, 0.f, 0.f};
        float ar[4] = {0.f, 0.f, 0.f, 0.f};
#pragma unroll
        for (int q = 0; q < 4; ++q) {
            const float4 wzq = *(const float4*)(bz + 4 * q);
            const float4 wrq = *(const float4*)(br + 4 * q);
#pragma unroll
            for (int b = 0; b < 4; ++b) {
                const float4 xq = *(const float4*)(&sXH[b][k0 + 4 * q]);
                az[b] = dot4(wzq, xq, az[b]);
                ar[b] = dot4(wrq, xq, ar[b]);
            }
        }
#pragma unroll
        for (int b = 0; b < 4; ++b) {
            sPA[0][b][wv][j] = az[b];
            sPA[1][b][wv][j] = ar[b];
        }
        if (isE) {
            float ac[4] = {0.f, 0.f, 0.f, 0.f};
#pragma unroll
            for (int q = 0; q < 4; ++q) {
                const float4 wcq = *(const float4*)(bc + 4 * q);
#pragma unroll
                for (int b = 0; b < 4; ++b) {
                    const float4 xq = *(const float4*)(&sXH[b][(k0 - 64) + 4 * q]);
                    ac[b] = dot4(wcq, xq, ac[b]);
                }
            }
#pragma unroll
            for (int b = 0; b < 4; ++b) sPC[b][wv][j] = ac[b];
        }
        __syncthreads();

        // ---- Reduce 1: all 512 threads; slot = (g, b, j) ----
        {
            const int g = tid >> 8, b = (tid >> 6) & 3;
            float s0 = sPA[g][b][0][j] + sPA[g][b][1][j];
            float s1 = sPA[g][b][2][j] + sPA[g][b][3][j];
            float s2 = sPA[g][b][4][j] + sPA[g][b][5][j];
            float s3 = sPA[g][b][6][j] + sPA[g][b][7][j];
            const float gt = fast_sigmoid((s0 + s1) + (s2 + s3));
            if (g == 0) sZ[b][j] = gt;
            else        sRH[b][j] = gt * sXH[b][64 + j];
        }
        __syncthreads();

        // ---- Phase B: cand-rh slices (L waves) ----
        if (!isE) {
            float ac[4] = {0.f, 0.f, 0.f, 0.f};
#pragma unroll
            for (int q = 0; q < 4; ++q) {
                const float4 wcq = *(const float4*)(bc + 4 * q);
#pragma unroll
                for (int b = 0; b < 4; ++b) {
                    const float4 rq = *(const float4*)(&sRH[b][k0 + 4 * q]);
                    ac[b] = dot4(wcq, rq, ac[b]);
                }
            }
#pragma unroll
            for (int b = 0; b < 4; ++b) sPC[b][wv][j] = ac[b];
        }
        __syncthreads();

        // ---- Reduce 2 + state update (waves 0-3); x commit (waves 4-7) ----
        if (tid < 256) {
            const int b = tid >> 6;
            float s0 = sPC[b][0][j] + sPC[b][1][j];
            float s1 = sPC[b][2][j] + sPC[b][3][j];
            float s2 = sPC[b][4][j] + sPC[b][5][j];
            float s3 = sPC[b][6][j] + sPC[b][7][j];
            const float hc = fast_tanh((s0 + s1) + (s2 + s3));
            const float z  = sZ[b][j];
            const float ho = sXH[b][64 + j];
            const float hn = fmaf(z, hc - ho, ho);
            sXH[b][64 + j] = hn;
            out[(size_t)t * (B_SZ * HD) + (size_t)(row0 + b) * HD + j] = hn;
            if (t == L_SEQ - 1)
                out[(size_t)L_SEQ * B_SZ * HD + (size_t)(row0 + b) * HD + j] = hn;
        } else {
            if (t < L_SEQ - 1) sXH[bE][j] = ev;   // x for step t+1
        }
        __syncthreads();
    }
}

extern "C" void kernel_launch(void* const* d_in, const int* in_sizes, int n_in,
                              void* d_out, int out_size, void* d_ws, size_t ws_size,
                              hipStream_t stream) {
    (void)in_sizes; (void)n_in; (void)out_size; (void)d_ws; (void)ws_size;
    const int*   x   = (const int*)  d_in[0];
    const float* emb = (const float*)d_in[1];
    const float* Wz  = (const float*)d_in[2];
    const float* Wr  = (const float*)d_in[3];
    const float* Wh  = (const float*)d_in[4];
    float* out = (float*)d_out;

    gru_fused_kernel<<<dim3(B_SZ / 4), dim3(512), 0, stream>>>(x, emb, Wz, Wr, Wh, out);
}